// Round 1
// baseline (217.791 us; speedup 1.0000x reference)
//
#include <hip/hip_runtime.h>

// Combine: out[b,:] = branches[argmax(gate[b,:4])][b,:]
// B=4096 rows, D=4096 fp32/row, N=4 branches. Memory-bound select-copy.
//
// v2: fix MLP. Previous kernel compiled to VGPR_Count=8 => one float4 in
// flight per thread (load->waitcnt->store serial chain). Now: 2 rows/block,
// all 8 float4 loads issued into named registers before any store
// (8 outstanding VMEM ops/thread), then 8 nontemporal stores so the
// write-once output doesn't evict the L3-resident branch rows.

#define B 4096
#define D 4096

typedef float f32x4 __attribute__((ext_vector_type(4)));

__global__ __launch_bounds__(256) void combine_kernel(
    const float* __restrict__ b0, const float* __restrict__ b1,
    const float* __restrict__ b2, const float* __restrict__ b3,
    const float* __restrict__ gate, float* __restrict__ out) {

    const int row0 = blockIdx.x * 2;
    const int t = threadIdx.x;

    // Per-row branch-pointer select (first-occurrence argmax, strict > to
    // match jnp.argmax tie-break). Wave-uniform per row -> no divergence.
    const float* s[2];
    #pragma unroll
    for (int r = 0; r < 2; ++r) {
        const int row = row0 + r;
        f32x4 g = ((const f32x4*)gate)[row];
        int idx = 0;
        float best = g.x;
        if (g.y > best) { best = g.y; idx = 1; }
        if (g.z > best) { best = g.z; idx = 2; }
        if (g.w > best) { best = g.w; idx = 3; }
        const float* p = (idx == 0) ? b0 : (idx == 1) ? b1 : (idx == 2) ? b2 : b3;
        s[r] = p + (size_t)row * D;
    }

    const f32x4* s0 = (const f32x4*)s[0];
    const f32x4* s1 = (const f32x4*)s[1];
    f32x4* d0 = (f32x4*)(out + (size_t)row0 * D);
    f32x4* d1 = (f32x4*)(out + (size_t)(row0 + 1) * D);

    // 1024 float4 per row / 256 threads = 4 per thread per row.
    // Issue all 8 loads first (32 data VGPRs) -> 8 outstanding VMEM ops.
    f32x4 v0 = s0[t];
    f32x4 v1 = s0[t + 256];
    f32x4 v2 = s0[t + 512];
    f32x4 v3 = s0[t + 768];
    f32x4 w0 = s1[t];
    f32x4 w1 = s1[t + 256];
    f32x4 w2 = s1[t + 512];
    f32x4 w3 = s1[t + 768];

    // Nontemporal: out is write-once, never re-read; don't allocate in L2/L3.
    __builtin_nontemporal_store(v0, &d0[t]);
    __builtin_nontemporal_store(v1, &d0[t + 256]);
    __builtin_nontemporal_store(v2, &d0[t + 512]);
    __builtin_nontemporal_store(v3, &d0[t + 768]);
    __builtin_nontemporal_store(w0, &d1[t]);
    __builtin_nontemporal_store(w1, &d1[t + 256]);
    __builtin_nontemporal_store(w2, &d1[t + 512]);
    __builtin_nontemporal_store(w3, &d1[t + 768]);
}

extern "C" void kernel_launch(void* const* d_in, const int* in_sizes, int n_in,
                              void* d_out, int out_size, void* d_ws, size_t ws_size,
                              hipStream_t stream) {
    const float* b0   = (const float*)d_in[0];
    const float* b1   = (const float*)d_in[1];
    const float* b2   = (const float*)d_in[2];
    const float* b3   = (const float*)d_in[3];
    const float* gate = (const float*)d_in[4];
    float* out = (float*)d_out;

    combine_kernel<<<B / 2, 256, 0, stream>>>(b0, b1, b2, b3, gate, out);
}